// Round 1
// baseline (671.219 us; speedup 1.0000x reference)
//
#include <hip/hip_runtime.h>

// CharRNN fused: B=256, L=1024, V=40, H=128. One block/CU, 256 thr = 4 waves.
// R5 structure: j-parallel, LDS-broadcast h.
//   h_t lives in double-buffered LDS hbuf[2][128]. Each wave owns a j-quarter
//   with FULL k: lane pair (l, l+32) computes j = 32w+(l&31); lane half l<32
//   sums k in [0,64), half l>=32 sums k in [64,128). h read as ds_read_b128
//   with 2 distinct addrs/wave (2-way = free); cross-half reduce is ONE
//   __shfl_xor(acc,32). This removes (a) the 32 v_readlane/step SGPR-hazard
//   chain and (b) the part[] cross-wave LDS reduce round-trip of R3/R4; the
//   remaining per-step LDS round-trip latency hides under the 96-FMA stream.
// Logits keep the proven lpart/burst scheme (v = lane<40, wave k-quarter),
// with h read via 8 UNIFORM ds_read_b128 (broadcast, conflict-free).

#define BB 256
#define LL 1024
#define VV 40
#define HH 128
#define WIN 32

__device__ __forceinline__ float fast_tanh(float x) {
    // tanh(x) = 1 - 2/(exp(2x)+1); overflow -> inf -> rcp -> 0 -> +1 (correct)
    float e = __expf(2.0f * x);
    float r = __builtin_amdgcn_rcpf(e + 1.0f);
    return 1.0f - 2.0f * r;
}

__global__ __launch_bounds__(256, 1) void rnn_fused(
    const int*   __restrict__ x,       // [B,L]
    const float* __restrict__ hidden,  // [B,H]
    const float* __restrict__ emb,     // [V,H]
    const float* __restrict__ Wh,      // [H,H]
    const float* __restrict__ Wo,      // [V,H]
    const float* __restrict__ b_h,     // [H]
    const float* __restrict__ b_y,     // [V]
    float*       __restrict__ out)     // [B*L*V logits][B*H final_hidden]
{
    __shared__ float emb_s[VV * HH];        // 20 KB (b_h folded in)
    __shared__ float hbuf[2][HH];           //  1 KB  double-buffered hidden
    __shared__ float lpart[WIN][4][48];     // 24 KB  logit partials (pad 40->48)
    __shared__ float bys[VV];
    __shared__ int   xbuf[LL];              //  4 KB
    // ~50.3 KB static LDS

    const int tid  = threadIdx.x;
    const int b    = blockIdx.x;
    const int w    = tid >> 6;          // wave 0..3
    const int lane = tid & 63;
    const int jq   = (w << 5) + (lane & 31);  // this lane's output j
    const int kh   = (lane & 32) << 1;        // k-half base: 0 or 64
    const int kq   = w << 5;                  // wave's logit k-quarter

    // ---- stage x, embedding(+b_h), b_y, initial hidden ----
    {
        const int4* xg = (const int4*)(x + (size_t)b * LL);
        int4* xs = (int4*)xbuf;
        for (int i = tid; i < LL / 4; i += 256) xs[i] = xg[i];
    }
    for (int i = tid; i < VV * HH; i += 256)
        emb_s[i] = emb[i] + b_h[i & (HH - 1)];
    if (tid < VV) bys[tid] = b_y[tid];
    if (tid < HH) hbuf[0][tid] = hidden[(size_t)b * HH + tid];

    // ---- weights into registers ----
    // wreg[i] = Wh[jq][kh + 4i .. kh + 4i + 3]   (64 floats: full k-half of row jq)
    // worg[i] = Wo[min(lane,39)][kq + 4i .. +3]  (32 floats: wave's k-quarter)
    float4 wreg[16], worg[8];
    {
        const float4* p0 = (const float4*)(Wh + (size_t)jq * HH + kh);
        int vrow = (lane < VV) ? lane : 0;
        const float4* p2 = (const float4*)(Wo + (size_t)vrow * HH + kq);
        #pragma unroll
        for (int i = 0; i < 16; i++) wreg[i] = p0[i];
        #pragma unroll
        for (int i = 0; i < 8; i++) worg[i] = p2[i];
    }
    __syncthreads();

    int p = 0;
    int idx_cur = xbuf[0];
    float hlast = 0.f;

    for (int t = 0; t < LL; ++t) {
        int tn = t + 1; if (tn > LL - 1) tn = LL - 1;
        int idx_next = xbuf[tn];
        // e for THIS step (issued early; FMA stream hides the LDS latency)
        float e_cur = emb_s[idx_cur * HH + jq];   // 2 lanes/addr -> broadcast

        // ---- h_{t-1} from LDS: 16x b128 (2 addrs/wave) + 8x b128 (uniform) ----
        const float4* hp = (const float4*)(&hbuf[p][kh]);
        const float4* lp = (const float4*)(&hbuf[p][kq]);
        float4 hv[16], lv[8];
        #pragma unroll
        for (int i = 0; i < 16; i++) hv[i] = hp[i];
        #pragma unroll
        for (int i = 0; i < 8; i++) lv[i] = lp[i];

        // ---- main dot: my j, my k-half (64 FMA, 4 chains) ----
        float a0 = 0.f, a1 = 0.f, a2 = 0.f, a3 = 0.f;
        #pragma unroll
        for (int i = 0; i < 16; i++) {
            a0 = fmaf(hv[i].x, wreg[i].x, a0);
            a1 = fmaf(hv[i].y, wreg[i].y, a1);
            a2 = fmaf(hv[i].z, wreg[i].z, a2);
            a3 = fmaf(hv[i].w, wreg[i].w, a3);
        }
        // ---- logit partial: v = lane(<40), wave's k-quarter (32 FMA, 4 chains) ----
        float l0 = 0.f, l1 = 0.f, l2 = 0.f, l3 = 0.f;
        #pragma unroll
        for (int i = 0; i < 8; i++) {
            l0 = fmaf(lv[i].x, worg[i].x, l0);
            l1 = fmaf(lv[i].y, worg[i].y, l1);
            l2 = fmaf(lv[i].z, worg[i].z, l2);
            l3 = fmaf(lv[i].w, worg[i].w, l3);
        }
        float lacc = (l0 + l1) + (l2 + l3);

        // ---- cross-half reduce + tanh ----
        float acc = (a0 + a1) + (a2 + a3);
        float oth = __shfl_xor(acc, 32);          // single cross-lane op
        float h   = fast_tanh(acc + oth + e_cur); // both halves compute (same value)
        hlast = h;

        if (t != 0 && lane < VV) lpart[(t - 1) & (WIN - 1)][w][lane] = lacc;
        if (lane < 32) hbuf[p ^ 1][jq] = h;       // 32 consec addrs, conflict-free
        __syncthreads();

        // ---- burst: reduce+store logit rows [t-32, t) ----
        if (t >= WIN && (t & (WIN - 1)) == 0) {
            const int rbase = t - WIN;
            #pragma unroll
            for (int q = 0; q < 5; ++q) {
                int o  = tid + 256 * q;        // 0..1279
                int tp = o / 40;
                int v  = o - 40 * tp;
                float sm = lpart[tp][0][v] + lpart[tp][1][v]
                         + lpart[tp][2][v] + lpart[tp][3][v] + bys[v];
                out[(size_t)b * LL * VV + (size_t)(rbase + tp) * VV + v] = sm;
            }
            __syncthreads();   // next step's lpart[0] write must wait
        }
        idx_cur = idx_next;
        p ^= 1;
    }

    // ---- epilogue: logits for row L-1 from h_{L-1} (in hbuf[p]), last burst ----
    {
        const float4* lp = (const float4*)(&hbuf[p][kq]);
        float4 lv[8];
        #pragma unroll
        for (int i = 0; i < 8; i++) lv[i] = lp[i];
        float l0 = 0.f, l1 = 0.f, l2 = 0.f, l3 = 0.f;
        #pragma unroll
        for (int i = 0; i < 8; i++) {
            l0 = fmaf(lv[i].x, worg[i].x, l0);
            l1 = fmaf(lv[i].y, worg[i].y, l1);
            l2 = fmaf(lv[i].z, worg[i].z, l2);
            l3 = fmaf(lv[i].w, worg[i].w, l3);
        }
        float lacc = (l0 + l1) + (l2 + l3);
        if (lane < VV) lpart[(LL - 1) & (WIN - 1)][w][lane] = lacc;
        __syncthreads();
        const int rbase = LL - WIN;
        #pragma unroll
        for (int q = 0; q < 5; ++q) {
            int o  = tid + 256 * q;
            int tp = o / 40;
            int v  = o - 40 * tp;
            float sm = lpart[tp][0][v] + lpart[tp][1][v]
                     + lpart[tp][2][v] + lpart[tp][3][v] + bys[v];
            out[(size_t)b * LL * VV + (size_t)(rbase + tp) * VV + v] = sm;
        }
        // final hidden
        if (lane < 32)
            out[(size_t)BB * LL * VV + (size_t)b * HH + jq] = hlast;
    }
}

extern "C" void kernel_launch(void* const* d_in, const int* in_sizes, int n_in,
                              void* d_out, int out_size, void* d_ws, size_t ws_size,
                              hipStream_t stream) {
    const int*   x      = (const int*)  d_in[0];
    const float* hidden = (const float*)d_in[1];
    const float* emb    = (const float*)d_in[2];
    const float* Wh     = (const float*)d_in[3];
    const float* Wo     = (const float*)d_in[4];
    const float* bh     = (const float*)d_in[5];
    const float* by     = (const float*)d_in[6];
    float*       out    = (float*)      d_out;

    rnn_fused<<<dim3(BB), dim3(256), 0, stream>>>(x, hidden, emb, Wh, Wo, bh, by, out);
}

// Round 2
// 601.690 us; speedup vs baseline: 1.1156x; 1.1156x over previous
//
#include <hip/hip_runtime.h>

// CharRNN fused: B=256, L=1024, V=40, H=128. One block/CU, 512 thr = 8 waves
// = 2 waves/SIMD (TLP to hide the reduce/barrier latency R5 exposed).
//
// R6 structure: k-parallel, register-resident h, 8-way k-split.
//   Wave w owns k in [16w,16w+16). Lane k'<16 of wave w holds h[16w+k'] in
//   hreg. Per step: 16-iteration readlane broadcast loop (VALU, no LDS!)
//   computing 3 fused dots: acc0 (j=lane), acc1 (j=lane+64), lacc (v=lane<40).
//   Partials go through a tiny double-buffered LDS buffer part[2][8][128];
//   after ONE barrier, wave w reduces only its own j-range [16w,16w+16)
//   (8 b32 reads + 7 adds + tanh) -> hreg for next step. h never hits LDS.
//
// R5 post-mortem drove two fixes:
//   1. AGPR spill: VGPR_Count=104 < live weights => compiler parked wreg in
//      AGPRs, v_accvgpr_read per FMA (~2x VALU, VALUBusy 34.5% vs expected
//      16%). Fix: only 48 persistent floats/lane + in-loop asm "+v" pin.
//   2. Occupancy 11.9% = 1 wave/SIMD: stalls fully exposed. Fix: 8 waves.

#define BB 256
#define LL 1024
#define VV 40
#define HH 128
#define WIN 16

__device__ __forceinline__ float fast_tanh(float x) {
    // tanh(x) = 1 - 2/(exp(2x)+1); overflow -> inf -> rcp -> 0 -> +1 (correct)
    float e = __expf(2.0f * x);
    float r = __builtin_amdgcn_rcpf(e + 1.0f);
    return 1.0f - 2.0f * r;
}

__device__ __forceinline__ float bcast(float v, int k) {
    return __int_as_float(__builtin_amdgcn_readlane(__float_as_int(v), k));
}

__global__ __launch_bounds__(512, 2) void rnn_fused(
    const int*   __restrict__ x,       // [B,L]
    const float* __restrict__ hidden,  // [B,H]
    const float* __restrict__ emb,     // [V,H]
    const float* __restrict__ Wh,      // [H,H]
    const float* __restrict__ Wo,      // [V,H]
    const float* __restrict__ b_h,     // [H]
    const float* __restrict__ b_y,     // [V]
    float*       __restrict__ out)     // [B*L*V logits][B*H final_hidden]
{
    __shared__ float emb_s[VV * HH];        // 20 KB (b_h folded in)
    __shared__ float part[2][8][HH];        //  8 KB  main-dot partials (dbuf)
    __shared__ float lpart[WIN][8][48];     // 24 KB  logit partials (pad 40->48)
    __shared__ float bys[VV];
    __shared__ int   xbuf[LL];              //  4 KB
    // ~56.2 KB static LDS

    const int tid  = threadIdx.x;
    const int b    = blockIdx.x;
    const int w    = tid >> 6;          // wave 0..7
    const int lane = tid & 63;
    const int kq   = w << 4;            // wave's k-sixteenth base

    // ---- stage x, embedding(+b_h), b_y ----
    {
        const int4* xg = (const int4*)(x + (size_t)b * LL);
        int4* xs = (int4*)xbuf;
        for (int i = tid; i < LL / 4; i += 512) xs[i] = xg[i];
    }
    for (int i = tid; i < VV * HH; i += 512)
        emb_s[i] = emb[i] + b_h[i & (HH - 1)];
    if (tid < VV) bys[tid] = b_y[tid];

    // ---- weights into registers (48 floats/lane) ----
    // wreg0[k] = Wh[lane][kq+k], wreg1[k] = Wh[lane+64][kq+k],
    // woreg[k] = Wo[min(lane,39)][kq+k]
    float wreg0[16], wreg1[16], woreg[16];
    {
        const float4* p0 = (const float4*)(Wh + (size_t)lane * HH + kq);
        const float4* p1 = (const float4*)(Wh + (size_t)(lane + 64) * HH + kq);
        int vrow = (lane < VV) ? lane : 0;
        const float4* p2 = (const float4*)(Wo + (size_t)vrow * HH + kq);
        #pragma unroll
        for (int i = 0; i < 4; i++) {
            float4 a = p0[i], c = p1[i], d = p2[i];
            wreg0[4*i+0] = a.x; wreg0[4*i+1] = a.y; wreg0[4*i+2] = a.z; wreg0[4*i+3] = a.w;
            wreg1[4*i+0] = c.x; wreg1[4*i+1] = c.y; wreg1[4*i+2] = c.z; wreg1[4*i+3] = c.w;
            woreg[4*i+0] = d.x; woreg[4*i+1] = d.y; woreg[4*i+2] = d.z; woreg[4*i+3] = d.w;
        }
    }
    float hreg = 0.f;
    if (lane < 16) hreg = hidden[(size_t)b * HH + kq + lane];
    __syncthreads();

    int p = 0;
    int idx_cur = xbuf[0];

    for (int t = 0; t < LL; ++t) {
        // Pin the 48 persistent weights to architectural VGPRs every step:
        // prevents the allocator from parking them in AGPRs (R5: per-FMA
        // v_accvgpr_read doubled VALU issue).
        asm volatile("" :
            "+v"(wreg0[0]), "+v"(wreg0[1]), "+v"(wreg0[2]), "+v"(wreg0[3]),
            "+v"(wreg0[4]), "+v"(wreg0[5]), "+v"(wreg0[6]), "+v"(wreg0[7]),
            "+v"(wreg0[8]), "+v"(wreg0[9]), "+v"(wreg0[10]), "+v"(wreg0[11]),
            "+v"(wreg0[12]), "+v"(wreg0[13]), "+v"(wreg0[14]), "+v"(wreg0[15]));
        asm volatile("" :
            "+v"(wreg1[0]), "+v"(wreg1[1]), "+v"(wreg1[2]), "+v"(wreg1[3]),
            "+v"(wreg1[4]), "+v"(wreg1[5]), "+v"(wreg1[6]), "+v"(wreg1[7]),
            "+v"(wreg1[8]), "+v"(wreg1[9]), "+v"(wreg1[10]), "+v"(wreg1[11]),
            "+v"(wreg1[12]), "+v"(wreg1[13]), "+v"(wreg1[14]), "+v"(wreg1[15]));
        asm volatile("" :
            "+v"(woreg[0]), "+v"(woreg[1]), "+v"(woreg[2]), "+v"(woreg[3]),
            "+v"(woreg[4]), "+v"(woreg[5]), "+v"(woreg[6]), "+v"(woreg[7]),
            "+v"(woreg[8]), "+v"(woreg[9]), "+v"(woreg[10]), "+v"(woreg[11]),
            "+v"(woreg[12]), "+v"(woreg[13]), "+v"(woreg[14]), "+v"(woreg[15]));

        int tn = t + 1; if (tn > LL - 1) tn = LL - 1;
        int idx_next = xbuf[tn];
        // e for THIS step (issued early; k-loop hides the LDS latency)
        float e_cur = emb_s[idx_cur * HH + kq + (lane & 15)];

        // ---- broadcast k-loop: partials over my wave's k-sixteenth ----
        float acc0 = 0.f, acc1 = 0.f, lacc = 0.f;
        #pragma unroll
        for (int k = 0; k < 16; ++k) {
            float s = bcast(hreg, k);          // h_{t-1}[kq+k], VALU broadcast
            acc0 = fmaf(s, wreg0[k], acc0);    // j = lane
            acc1 = fmaf(s, wreg1[k], acc1);    // j = lane+64
            lacc = fmaf(s, woreg[k], lacc);    // v = lane (<40)
        }

        part[p][w][lane]      = acc0;
        part[p][w][lane + 64] = acc1;
        if (t != 0 && lane < VV) lpart[(t - 1) & (WIN - 1)][w][lane] = lacc;
        __syncthreads();

        // ---- K-reduction + tanh: my wave's own j-sixteenth ----
        if (lane < 16) {
            int j = kq + lane;
            float s0 = part[p][0][j] + part[p][1][j];
            float s1 = part[p][2][j] + part[p][3][j];
            float s2 = part[p][4][j] + part[p][5][j];
            float s3 = part[p][6][j] + part[p][7][j];
            hreg = fast_tanh(((s0 + s1) + (s2 + s3)) + e_cur);
        }

        // ---- burst: reduce+store logit rows [t-16, t) ----
        if (t >= WIN && (t & (WIN - 1)) == 0) {
            const int rbase = t - WIN;
            {
                int o  = tid;                  // 0..511
                int tp = o / 40;
                int v  = o - 40 * tp;
                float sm = bys[v];
                #pragma unroll
                for (int g = 0; g < 8; ++g) sm += lpart[tp][g][v];
                out[(size_t)b * LL * VV + (size_t)(rbase + tp) * VV + v] = sm;
            }
            if (tid < 128) {
                int o  = tid + 512;            // 512..639
                int tp = o / 40;
                int v  = o - 40 * tp;
                float sm = bys[v];
                #pragma unroll
                for (int g = 0; g < 8; ++g) sm += lpart[tp][g][v];
                out[(size_t)b * LL * VV + (size_t)(rbase + tp) * VV + v] = sm;
            }
            __syncthreads();   // next step's lpart[0] write must wait
        }

        idx_cur = idx_next;
        p ^= 1;
    }

    // ---- epilogue: logits for row L-1 from final h, then last burst ----
    {
        float lacc = 0.f;
        #pragma unroll
        for (int k = 0; k < 16; ++k) {
            float s = bcast(hreg, k);
            lacc = fmaf(s, woreg[k], lacc);
        }
        if (lane < VV) lpart[(LL - 1) & (WIN - 1)][w][lane] = lacc;
        __syncthreads();
        const int rbase = LL - WIN;
        {
            int o  = tid;
            int tp = o / 40;
            int v  = o - 40 * tp;
            float sm = bys[v];
            #pragma unroll
            for (int g = 0; g < 8; ++g) sm += lpart[tp][g][v];
            out[(size_t)b * LL * VV + (size_t)(rbase + tp) * VV + v] = sm;
        }
        if (tid < 128) {
            int o  = tid + 512;
            int tp = o / 40;
            int v  = o - 40 * tp;
            float sm = bys[v];
            #pragma unroll
            for (int g = 0; g < 8; ++g) sm += lpart[tp][g][v];
            out[(size_t)b * LL * VV + (size_t)(rbase + tp) * VV + v] = sm;
        }
        // final hidden
        if (lane < 16)
            out[(size_t)BB * LL * VV + (size_t)b * HH + kq + lane] = hreg;
    }
}

extern "C" void kernel_launch(void* const* d_in, const int* in_sizes, int n_in,
                              void* d_out, int out_size, void* d_ws, size_t ws_size,
                              hipStream_t stream) {
    const int*   x      = (const int*)  d_in[0];
    const float* hidden = (const float*)d_in[1];
    const float* emb    = (const float*)d_in[2];
    const float* Wh     = (const float*)d_in[3];
    const float* Wo     = (const float*)d_in[4];
    const float* bh     = (const float*)d_in[5];
    const float* by     = (const float*)d_in[6];
    float*       out    = (float*)      d_out;

    rnn_fused<<<dim3(BB), dim3(512), 0, stream>>>(x, hidden, emb, Wh, Wo, bh, by, out);
}